// Round 5
// baseline (531.266 us; speedup 1.0000x reference)
//
#include <hip/hip_runtime.h>
#include <hip/hip_bf16.h>
#include <cstdint>

typedef __bf16 bf16x8 __attribute__((ext_vector_type(8)));
typedef __bf16 bf16x4 __attribute__((ext_vector_type(4)));
typedef float  f4     __attribute__((ext_vector_type(4)));

constexpr int BATCH   = 2;
constexpr int LSEQ    = 2048;
constexpr int NH      = 2048;
constexpr int INNER   = 4096;
constexpr int DSTATE  = 128;
constexpr int CONVD   = 4352;
constexpr int HEADS   = 64;
constexpr int HDIM    = 64;
constexpr int NPROJ   = 8512;
constexpr int NPROJ_P = 8704;   // padded to 256 multiple
constexpr int NC      = 16;
constexpr int CH      = 128;
constexpr int ROWS    = BATCH * LSEQ;
constexpr int NBC     = BATCH * NC;   // 32

__device__ __forceinline__ f4 f4zero() { f4 v; v.x=0.f; v.y=0.f; v.z=0.f; v.w=0.f; return v; }

__device__ __forceinline__ void gload16(const __bf16* g, const char* l) {
    __builtin_amdgcn_global_load_lds((const __attribute__((address_space(1))) void*)g,
                                     (__attribute__((address_space(3))) void*)l, 16, 0, 0);
}

// ---------------- cast f32 -> bf16 ----------------
__global__ __launch_bounds__(256) void k_cast_bf16(const float* __restrict__ in,
                                                   __bf16* __restrict__ out, int n4) {
    int i = blockIdx.x * 256 + threadIdx.x;
    if (i >= n4) return;
    f4 v = ((const f4*)in)[i];
    bf16x4 o;
    o[0] = (__bf16)v.x; o[1] = (__bf16)v.y; o[2] = (__bf16)v.z; o[3] = (__bf16)v.w;
    ((bf16x4*)out)[i] = o;
}

// ---------------- transpose + cast: in f32 (R x C) -> out bf16 (Cp x R) ----------------
__global__ __launch_bounds__(256) void k_transpose_cast(const float* __restrict__ in,
                                                        __bf16* __restrict__ out,
                                                        int R, int C, int Cp) {
    __shared__ float tile[32][33];
    int bn = blockIdx.x * 32, bk = blockIdx.y * 32;
    int tx = threadIdx.x & 31, ty = threadIdx.x >> 5;
#pragma unroll
    for (int i = 0; i < 4; ++i) {
        int k = bk + ty + i * 8, n = bn + tx;
        tile[ty + i * 8][tx] = (k < R && n < C) ? in[(size_t)k * C + n] : 0.f;
    }
    __syncthreads();
#pragma unroll
    for (int i = 0; i < 4; ++i) {
        int n = bn + ty + i * 8, k = bk + tx;
        if (n < Cp && k < R) out[(size_t)n * R + k] = (__bf16)tile[tx][ty + i * 8];
    }
}

// ============ 8-phase 256-tile GEMM: dbuf + front-loaded staging + counted vmcnt ============
// LDS per buffer: A region [kp(2)][row(BM)][32 bf16], then B region same with BN.
// XOR swizzle: k-slot bit1 ^= row bit3 (inverse on staging source, forward on reads).
// Block order: XCD-bijective chunks, column-major (blocks in a chunk share the B panel in L2).
template<int BM, int BN, int WM, int WN, int EPI>
__global__ __launch_bounds__(512, 2) void k_gemm8(
    const __bf16* __restrict__ A, const __bf16* __restrict__ Bt,
    const float* __restrict__ bias, float* __restrict__ Cf,
    __bf16* __restrict__ zf, __bf16* __restrict__ xbcpre, float* __restrict__ dtraw,
    int N, int K, int gridY) {
    extern __shared__ char smem[];
    constexpr int MFRAG = BM / (WM * 16);
    constexpr int NFRAG = BN / (WN * 16);
    constexpr int MH = MFRAG / 2, NH2 = NFRAG / 2;
    constexpr int ALINES = BM / 64, BLINES = BN / 64, LT = ALINES + BLINES;
    constexpr int ABYTES = BM * 128, BUFB = ABYTES + BN * 128;
    constexpr int LPPA = BM / 128, LPPB = BN / 128;

    int tid = threadIdx.x, lane = tid & 63, w = tid >> 6;
    int wm = w / WN, wn = w % WN;

    // XCD-bijective chunked swizzle, then column-major within the whole grid
    int bid = blockIdx.x;
    int q = gridDim.x >> 3;
    int wg = (bid & 7) * q + (bid >> 3);
    int bx = wg / gridY, by = wg - bx * gridY;
    int mBase = by * BM, nBase = bx * BN;

    // read-side lane constants
    int rl = lane & 15, rq = lane >> 4;
    int kslp = rq ^ (((rl >> 3) & 1) << 1);
    const int rdA = (wm * MFRAG * 16 + rl) * 64 + kslp * 16;
    const int rdB = ABYTES + (wn * NFRAG * 16 + rl) * 64 + kslp * 16;

    // stage-side lane constants (inverse swizzle on source)
    int lanep = lane ^ (((lane >> 5) & 1) << 1);
    int srs = lanep >> 2, sksl = lanep & 3;

    const __bf16* sA[ALINES];
#pragma unroll
    for (int li = 0; li < ALINES; ++li)
        sA[li] = A + (size_t)(mBase + (li % LPPA) * 128 + w * 16 + srs) * K + (li / LPPA) * 32 + sksl * 8;
    const __bf16* sB[BLINES];
#pragma unroll
    for (int li = 0; li < BLINES; ++li)
        sB[li] = Bt + (size_t)(nBase + (li % LPPB) * 128 + w * 16 + srs) * K + (li / LPPB) * 32 + sksl * 8;

    auto stage = [&](int buf, int line, int kt) {
        if (line < ALINES) {
            gload16(sA[line] + kt, smem + buf * BUFB + line * 8192 + w * 1024);
        } else {
            int lb = line - ALINES;
            gload16(sB[lb] + kt, smem + buf * BUFB + ABYTES + lb * 8192 + w * 1024);
        }
    };

    f4 acc[MFRAG][NFRAG];
#pragma unroll
    for (int i = 0; i < MFRAG; ++i)
#pragma unroll
        for (int j = 0; j < NFRAG; ++j) acc[i][j] = f4zero();

    const int nt = K >> 6;
    // prologue: tile 0 fully into buf0; early 2 lines of tile 1 into buf1
#pragma unroll
    for (int li = 0; li < LT; ++li) stage(0, li, 0);
    stage(1, 0, 64);
    stage(1, 1, 64);
    asm volatile("s_waitcnt vmcnt(2)" ::: "memory");
    __builtin_amdgcn_s_barrier();

    for (int t = 0; t < nt; ++t) {
        const int cur = t & 1;
        const int bufoff = cur * BUFB;
        const bool hasNext = (t + 1 < nt);
        const int ktn = (t + 1) << 6;
#pragma unroll
        for (int p = 0; p < 4; ++p) {
            const int mh = p >> 1, nh = p & 1;
            bf16x8 af[MH][2], bv[NH2][2];
#pragma unroll
            for (int mi = 0; mi < MH; ++mi)
#pragma unroll
                for (int ks = 0; ks < 2; ++ks)
                    af[mi][ks] = *(const bf16x8*)(smem + bufoff + ks * (BM * 64) + rdA + (mh * MH + mi) * 1024);
#pragma unroll
            for (int ni = 0; ni < NH2; ++ni)
#pragma unroll
                for (int ks = 0; ks < 2; ++ks)
                    bv[ni][ks] = *(const bf16x8*)(smem + bufoff + ks * (BN * 64) + rdB + (nh * NH2 + ni) * 1024);
            if (hasNext) {
                // front-loaded: stage 3 lines in phase 0 and 3 in phase 1 (lines 0,1
                // were issued at the previous tile boundary)
#pragma unroll
                for (int i = 0; i < 3; ++i) {
                    int li = 2 + p * 3 + i;
                    if (li < LT) stage(cur ^ 1, li, ktn);
                }
            }
            __builtin_amdgcn_s_barrier();
            asm volatile("s_waitcnt lgkmcnt(0)" ::: "memory");
            __builtin_amdgcn_sched_barrier(0);
            __builtin_amdgcn_s_setprio(1);
#pragma unroll
            for (int mi = 0; mi < MH; ++mi)
#pragma unroll
                for (int ni = 0; ni < NH2; ++ni)
#pragma unroll
                    for (int ks = 0; ks < 2; ++ks)
                        acc[mh * MH + mi][nh * NH2 + ni] =
                            __builtin_amdgcn_mfma_f32_16x16x32_bf16(af[mi][ks], bv[ni][ks],
                                                                    acc[mh * MH + mi][nh * NH2 + ni], 0, 0, 0);
            __builtin_amdgcn_s_setprio(0);
            __builtin_amdgcn_s_barrier();
        }
        if (t + 2 < nt) {
            stage(cur, 0, (t + 2) << 6);
            stage(cur, 1, (t + 2) << 6);
            asm volatile("s_waitcnt vmcnt(2)" ::: "memory");
            __builtin_amdgcn_s_barrier();
        } else if (hasNext) {
            asm volatile("s_waitcnt vmcnt(0)" ::: "memory");
            __builtin_amdgcn_s_barrier();
        }
    }

    // epilogue: C/D layout col=lane&15, row=(lane>>4)*4+j
    int cl = lane & 15, rq4 = (lane >> 4) * 4;
#pragma unroll
    for (int nf = 0; nf < NFRAG; ++nf) {
        int col0 = nBase + wn * NFRAG * 16 + nf * 16;
        int col = col0 + cl;
        if constexpr (EPI == 1) {
            if (col0 >= NPROJ) continue;
            float bvv = bias[col];
#pragma unroll
            for (int mf = 0; mf < MFRAG; ++mf) {
#pragma unroll
                for (int j = 0; j < 4; ++j) {
                    int row = mBase + wm * MFRAG * 16 + mf * 16 + rq4 + j;
                    float v = acc[mf][nf][j] + bvv;
                    if (col0 < INNER) {
                        zf[(size_t)row * INNER + col] = (__bf16)v;
                    } else if (col0 < INNER + CONVD) {
                        xbcpre[(size_t)row * CONVD + (col - INNER)] = (__bf16)v;
                    } else {
                        dtraw[(size_t)row * HEADS + (col - INNER - CONVD)] = v;
                    }
                }
            }
        } else {
            float bvv = bias[col];
#pragma unroll
            for (int mf = 0; mf < MFRAG; ++mf)
#pragma unroll
                for (int j = 0; j < 4; ++j) {
                    int row = mBase + wm * MFRAG * 16 + mf * 16 + rq4 + j;
                    Cf[(size_t)row * N + col] = acc[mf][nf][j] + bvv;
                }
        }
    }
}

// ---------------- depthwise causal conv(4) + bias + silu ----------------
__global__ __launch_bounds__(256) void k_conv_silu(const __bf16* __restrict__ xbcpre,
                                                   const float* __restrict__ conv_w,
                                                   const float* __restrict__ conv_b,
                                                   __bf16* __restrict__ xbc) {
    int idx = blockIdx.x * 256 + threadIdx.x;
    int c8 = idx % (CONVD / 8);
    int bl = idx / (CONVD / 8);
    int l = bl & (LSEQ - 1);
    int c0 = c8 * 8;
    float acc[8];
    const f4* cb4 = (const f4*)(conv_b + c0);
    f4 b0 = cb4[0], b1 = cb4[1];
#pragma unroll
    for (int k = 0; k < 4; ++k) { acc[k] = b0[k]; acc[k + 4] = b1[k]; }
#pragma unroll
    for (int j = 0; j < 4; ++j) {
        int l2 = l + j - 3;
        if (l2 < 0) continue;
        bf16x8 xv = *(const bf16x8*)(xbcpre + (size_t)(bl + j - 3) * CONVD + c0);
        const f4* w4 = (const f4*)(conv_w + j * CONVD + c0);
        f4 w0 = w4[0], w1 = w4[1];
#pragma unroll
        for (int k = 0; k < 4; ++k) {
            acc[k]     += w0[k] * (float)xv[k];
            acc[k + 4] += w1[k] * (float)xv[k + 4];
        }
    }
    bf16x8 o;
#pragma unroll
    for (int k = 0; k < 8; ++k) {
        float a = acc[k];
        o[k] = (__bf16)(a / (1.f + expf(-a)));
    }
    *(bf16x8*)(xbc + (size_t)bl * CONVD + c0) = o;
}

// ---------------- dt = clip(softplus(raw+bias)), stored transposed [b,h][l] ----------------
__global__ __launch_bounds__(256) void k_dt(const float* __restrict__ dtraw,
                                            const float* __restrict__ dt_bias,
                                            float* __restrict__ dtp_t) {
    int idx = blockIdx.x * 256 + threadIdx.x;  // ROWS*HEADS
    int h = idx & 63;
    int bl = idx >> 6;
    int b = bl >> 11, l = bl & (LSEQ - 1);
    float raw = dtraw[idx] + dt_bias[h];
    float sp = raw > 20.f ? raw : log1pf(expf(raw));
    dtp_t[((size_t)(b * HEADS + h)) * LSEQ + l] = fminf(fmaxf(sp, 0.001f), 0.1f);
}

// ---------------- per-(b,c): transpose x-block and B-block ----------------
__global__ __launch_bounds__(256) void k_transpose_bc(const __bf16* __restrict__ xbc,
                                                      __bf16* __restrict__ xT,
                                                      __bf16* __restrict__ BtG) {
    int bid = blockIdx.x;                 // bc*132 + rt*66 + ct
    int ct = bid % 66;
    int rt = (bid / 66) & 1;
    int bc = bid / 132;
    __shared__ float T[64][65];
    int t = threadIdx.x;
    int lr0 = t >> 3, cg = t & 7;
#pragma unroll
    for (int it = 0; it < 2; ++it) {
        int lr = lr0 + it * 32;
        bf16x8 v = *(const bf16x8*)(xbc + (size_t)(bc * CH + rt * 64 + lr) * CONVD + ct * 64 + cg * 8);
#pragma unroll
        for (int j = 0; j < 8; ++j) T[lr][cg * 8 + j] = (float)v[j];
    }
    __syncthreads();
#pragma unroll
    for (int it = 0; it < 2; ++it) {
        int cl = lr0 + it * 32;
        int c = ct * 64 + cl;
        bf16x8 o;
#pragma unroll
        for (int j = 0; j < 8; ++j) o[j] = (__bf16)T[cg * 8 + j][cl];
        __bf16* dst = (c < INNER)
            ? xT  + ((size_t)bc * INNER + c) * CH + rt * 64 + cg * 8
            : BtG + ((size_t)bc * DSTATE + (c - INNER)) * CH + rt * 64 + cg * 8;
        *(bf16x8*)dst = o;
    }
}

// ---------------- cb[bc][l][s] = C[l]·B[s] (lower-tri) ----------------
__global__ __launch_bounds__(256) void k_cb(const __bf16* __restrict__ xbc,
                                            float* __restrict__ cbT) {
    int bid = blockIdx.x;  // bc*8 + lg
    int lg = bid & 7, bc = bid >> 3;
    int tid = threadIdx.x;
    int e0 = lg * 2048 + tid * 8;
    int l = e0 >> 7;
    int s0 = e0 & 127;
    const __bf16* Crow = xbc + (size_t)(bc * CH + l) * CONVD + INNER + DSTATE;
    const __bf16* B0   = xbc + (size_t)(bc * CH + s0) * CONVD + INNER;
    float acc[8];
#pragma unroll
    for (int j = 0; j < 8; ++j) acc[j] = 0.f;
    for (int n8 = 0; n8 < 16; ++n8) {
        bf16x8 cv = *(const bf16x8*)(Crow + n8 * 8);
        float cf[8];
#pragma unroll
        for (int k = 0; k < 8; ++k) cf[k] = (float)cv[k];
#pragma unroll
        for (int j = 0; j < 8; ++j) {
            bf16x8 bvv = *(const bf16x8*)(B0 + (size_t)j * CONVD + n8 * 8);
#pragma unroll
            for (int k = 0; k < 8; ++k) acc[j] += cf[k] * (float)bvv[k];
        }
    }
    float* dst = cbT + ((size_t)bc << 14) + (l << 7) + s0;
#pragma unroll
    for (int j = 0; j < 8; ++j) dst[j] = (s0 + j <= l) ? acc[j] : 0.f;
}

// ---------------- k_states (MFMA): states[p][n] = sum_l e[l]*X[l,p]*B[l,n] ----------------
__global__ __launch_bounds__(256) void k_states(const __bf16* __restrict__ xT,
                                                const __bf16* __restrict__ BtG,
                                                const float* __restrict__ dtp_t,
                                                const float* __restrict__ A_log,
                                                __bf16* __restrict__ states,
                                                float* __restrict__ acum_buf,
                                                float* __restrict__ aend_buf) {
    int bid = blockIdx.x;
    int h = bid & 63, c = (bid >> 6) & 15, b = bid >> 10;
    int bc = b * NC + c, bh = b * HEADS + h;
    int tid = threadIdx.x;
    int lane = tid & 63, w = tid >> 6;
    __shared__ __bf16 Ab[64 * 136];
    __shared__ __bf16 Bb[128 * 136];
    __shared__ float s_ac[128], s_dt[128], s_e[128];
    float a_h = -expf(A_log[h]);

    if (tid < 128) {
        float d = dtp_t[(size_t)bh * LSEQ + c * CH + tid];
        s_dt[tid] = d;
        s_ac[tid] = a_h * d;
    }
    __syncthreads();
    for (int offd = 1; offd < 128; offd <<= 1) {
        float v = 0.f;
        if (tid < 128 && tid >= offd) v = s_ac[tid - offd];
        __syncthreads();
        if (tid < 128) s_ac[tid] += v;
        __syncthreads();
    }
    float aend = s_ac[127];
    if (tid < 128) {
        s_e[tid] = expf(aend - s_ac[tid]) * s_dt[tid];
        acum_buf[((size_t)bh * NC + c) * CH + tid] = s_ac[tid];
    }
    if (tid == 0) aend_buf[bh * NC + c] = aend;
    __syncthreads();

    const __bf16* xrow = xT + ((size_t)bc * INNER + h * HDIM) * CH;
#pragma unroll
    for (int it = 0; it < 4; ++it) {
        int task = it * 256 + tid;
        int p = task >> 4, lg2 = task & 15;
        bf16x8 v = *(const bf16x8*)(xrow + (size_t)p * CH + lg2 * 8);
        bf16x8 o;
#pragma unroll
        for (int j = 0; j < 8; ++j) o[j] = (__bf16)((float)v[j] * s_e[lg2 * 8 + j]);
        *(bf16x8*)&Ab[p * 136 + lg2 * 8] = o;
    }
    const __bf16* brow = BtG + (size_t)bc * DSTATE * CH;
#pragma unroll
    for (int it = 0; it < 8; ++it) {
        int task = it * 256 + tid;
        int n = task >> 4, lg2 = task & 15;
        *(bf16x8*)&Bb[n * 136 + lg2 * 8] = *(const bf16x8*)(brow + (size_t)n * CH + lg2 * 8);
    }
    __syncthreads();

    int rl = lane & 15, kq = (lane >> 4) * 8, rq = lane >> 4;
    f4 acc[8];
#pragma unroll
    for (int i = 0; i < 8; ++i) acc[i] = f4zero();
#pragma unroll
    for (int ks = 0; ks < 4; ++ks) {
        int k0 = ks * 32;
        bf16x8 a = *(const bf16x8*)&Ab[(w * 16 + rl) * 136 + k0 + kq];
#pragma unroll
        for (int nf = 0; nf < 8; ++nf) {
            bf16x8 bfr = *(const bf16x8*)&Bb[(nf * 16 + rl) * 136 + k0 + kq];
            acc[nf] = __builtin_amdgcn_mfma_f32_16x16x32_bf16(a, bfr, acc[nf], 0, 0, 0);
        }
    }
    __syncthreads();
#pragma unroll
    for (int nf = 0; nf < 8; ++nf)
#pragma unroll
        for (int j = 0; j < 4; ++j)
            Ab[(w * 16 + rq * 4 + j) * 136 + nf * 16 + rl] = (__bf16)acc[nf][j];
    __syncthreads();
    __bf16* sbase = states + ((size_t)(bc * HEADS + h)) * (HDIM * DSTATE);
#pragma unroll
    for (int it = 0; it < 4; ++it) {
        int task = it * 256 + tid;
        int p = task >> 4, ng = task & 15;
        *(bf16x8*)(sbase + (size_t)p * DSTATE + ng * 8) = *(const bf16x8*)&Ab[p * 136 + ng * 8];
    }
}

// ---------------- inter-chunk state scan (in place, bf16), 8 slices per (b,h) ----------
__global__ __launch_bounds__(128) void k_scan(__bf16* __restrict__ states,
                                              const float* __restrict__ aend_buf) {
    int s = blockIdx.x & 7;
    int bh = blockIdx.x >> 3;
    int b = bh >> 6, h = bh & 63;
    int tid = threadIdx.x;
    size_t off = (size_t)s * 1024 + (size_t)tid * 8;
    float run[8];
#pragma unroll
    for (int j = 0; j < 8; ++j) run[j] = 0.f;
    for (int c = 0; c < NC; ++c) {
        float dec = expf(aend_buf[bh * NC + c]);
        __bf16* base = states + ((size_t)((b * NC + c) * HEADS + h)) * (HDIM * DSTATE) + off;
        bf16x8 sv = *(bf16x8*)base;
        bf16x8 o;
#pragma unroll
        for (int j = 0; j < 8; ++j) o[j] = (__bf16)run[j];
        *(bf16x8*)base = o;
#pragma unroll
        for (int j = 0; j < 8; ++j) run[j] = run[j] * dec + (float)sv[j];
    }
}

// ---------------- k_out (MFMA): y = exp(ac)*C·prev^T + M·X + D*x ----------------
__global__ __launch_bounds__(256) void k_out(const __bf16* __restrict__ xbc,
                                             const __bf16* __restrict__ xT,
                                             const float* __restrict__ dtp_t,
                                             const float* __restrict__ cbT,
                                             const __bf16* __restrict__ prev,
                                             const float* __restrict__ acum_buf,
                                             const float* __restrict__ D_param,
                                             __bf16* __restrict__ ybuf) {
    int bid = blockIdx.x;
    int h = bid & 63, c = (bid >> 6) & 15, b = bid >> 10;
    int bc = b * NC + c, bh = b * HEADS + h;
    int tid = threadIdx.x;
    int lane = tid & 63, w = tid >> 6;
    __shared__ __bf16 Ab[128 * 136];
    __shared__ __bf16 Bb[64 * 136];
    __shared__ float s_ac[128], s_dt[128];
    if (tid < 128) {
        s_ac[tid] = acum_buf[((size_t)bh * NC + c) * CH + tid];
        s_dt[tid] = dtp_t[(size_t)bh * LSEQ + c * CH + tid];
    }

#pragma unroll
    for (int it = 0; it < 8; ++it) {
        int task = it * 256 + tid;
        int l = task >> 4, ng = task & 15;
        *(bf16x8*)&Ab[l * 136 + ng * 8] =
            *(const bf16x8*)(xbc + (size_t)(bc * CH + l) * CONVD + INNER + DSTATE + ng * 8);
    }
    const __bf16* pbase = prev + ((size_t)(bc * HEADS + h)) * (HDIM * DSTATE);
#pragma unroll
    for (int it = 0; it < 4; ++it) {
        int task = it * 256 + tid;
        int p = task >> 4, ng = task & 15;
        *(bf16x8*)&Bb[p * 136 + ng * 8] = *(const bf16x8*)(pbase + (size_t)p * DSTATE + ng * 8);
    }
    __syncthreads();

    int rl = lane & 15, kq = (lane >> 4) * 8, rq = lane >> 4;
    f4 acc[2][4];
#pragma unroll
    for (int i = 0; i < 2; ++i)
#pragma unroll
        for (int j = 0; j < 4; ++j) acc[i][j] = f4zero();

#pragma unroll
    for (int ks = 0; ks < 4; ++ks) {
        int k0 = ks * 32;
        bf16x8 a0 = *(const bf16x8*)&Ab[(w * 32 + rl) * 136 + k0 + kq];
        bf16x8 a1 = *(const bf16x8*)&Ab[(w * 32 + 16 + rl) * 136 + k0 + kq];
#pragma unroll
        for (int nf = 0; nf < 4; ++nf) {
            bf16x8 bfr = *(const bf16x8*)&Bb[(nf * 16 + rl) * 136 + k0 + kq];
            acc[0][nf] = __builtin_amdgcn_mfma_f32_16x16x32_bf16(a0, bfr, acc[0][nf], 0, 0, 0);
            acc[1][nf] = __builtin_amdgcn_mfma_f32_16x16x32_bf16(a1, bfr, acc[1][nf], 0, 0, 0);
        }
    }
#pragma unroll
    for (int mf = 0; mf < 2; ++mf)
#pragma unroll
        for (int j = 0; j < 4; ++j) {
            float el = expf(s_ac[w * 32 + mf * 16 + rq * 4 + j]);
#pragma unroll
            for (int nf = 0; nf < 4; ++nf) acc[mf][nf][j] *= el;
        }
    __syncthreads();

    const float* cbb = cbT + ((size_t)bc << 14);
#pragma unroll
    for (int it = 0; it < 8; ++it) {
        int task = it * 256 + tid;
        int l = task >> 4, sg = task & 15;
        int s0 = sg * 8;
        const f4* cv4 = (const f4*)(cbb + (l << 7) + s0);
        f4 c0 = cv4[0], c1 = cv4[1];
        float acl = s_ac[l];
        bf16x8 o;
#pragma unroll
        for (int j = 0; j < 8; ++j) {
            int s = s0 + j;
            float cj = (j < 4) ? c0[j] : c1[j - 4];
            float m = 0.f;
            if (s <= l) m = cj * expf(acl - s_ac[s]) * s_dt[s];
            o[j] = (__bf16)m;
        }
        *(bf16x8*)&Ab[l * 136 + s0] = o;
    }
    const __bf16* xrow = xT + ((size_t)bc * INNER + h * HDIM) * CH;
#pragma unroll
    for (int it = 0; it < 4; ++it) {
        int task = it * 256 + tid;
        int p = task >> 4, lg2 = task & 15;
        *(bf16x8*)&Bb[p * 136 + lg2 * 8] = *(const bf16x8*)(xrow + (size_t)p * CH + lg2 * 8);
    }
    __syncthreads();

#pragma unroll
    for (int ks = 0; ks < 4; ++ks) {
        int k0 = ks * 32;
        bf16x8 a0 = *(const bf16x8*)&Ab[(w * 32 + rl) * 136 + k0 + kq];
        bf16x8 a1 = *(const bf16x8*)&Ab[(w * 32 + 16 + rl) * 136 + k0 + kq];
#pragma unroll
        for (int nf = 0; nf < 4; ++nf) {
            bf16x8 bfr = *(const bf16x8*)&Bb[(nf * 16 + rl) * 136 + k0 + kq];
            acc[0][nf] = __builtin_amdgcn_mfma_f32_16x16x32_bf16(a0, bfr, acc[0][nf], 0, 0, 0);
            acc[1][nf] = __builtin_amdgcn_mfma_f32_16x16x32_bf16(a1, bfr, acc[1][nf], 0, 0, 0);
        }
    }
    __syncthreads();

    float* yT = (float*)Ab;
#pragma unroll
    for (int mf = 0; mf < 2; ++mf)
#pragma unroll
        for (int nf = 0; nf < 4; ++nf)
#pragma unroll
            for (int j = 0; j < 4; ++j)
                yT[(w * 32 + mf * 16 + rq * 4 + j) * 68 + nf * 16 + rl] = acc[mf][nf][j];
    __syncthreads();

    float dh = D_param[h];
#pragma unroll
    for (int it = 0; it < 4; ++it) {
        int task = it * 256 + tid;
        int l = task >> 3, pg = task & 7;
        const f4* yv4 = (const f4*)&yT[l * 68 + pg * 8];
        f4 y0 = yv4[0], y1 = yv4[1];
        bf16x8 xv = *(const bf16x8*)(xbc + (size_t)(bc * CH + l) * CONVD + h * HDIM + pg * 8);
        bf16x8 o;
#pragma unroll
        for (int j = 0; j < 4; ++j) {
            o[j]     = (__bf16)(y0[j] + dh * (float)xv[j]);
            o[j + 4] = (__bf16)(y1[j] + dh * (float)xv[j + 4]);
        }
        *(bf16x8*)(ybuf + (size_t)(bc * CH + l) * INNER + h * HDIM + pg * 8) = o;
    }
}

// ---------------- gate (silu(z)) + RMSNorm, in place on ybuf ----------------
__global__ __launch_bounds__(256) void k_gate_norm(__bf16* __restrict__ ybuf,
                                                   const __bf16* __restrict__ zf,
                                                   const float* __restrict__ norm_w) {
    int row = blockIdx.x, tid = threadIdx.x;
    bf16x8* yrow = (bf16x8*)(ybuf + (size_t)row * INNER);
    const bf16x8* zrow = (const bf16x8*)(zf + (size_t)row * INNER);
    float v[2][8];
    float ss = 0.f;
#pragma unroll
    for (int i = 0; i < 2; ++i) {
        bf16x8 yv = yrow[i * 256 + tid];
        bf16x8 zv = zrow[i * 256 + tid];
#pragma unroll
        for (int j = 0; j < 8; ++j) {
            float z = (float)zv[j];
            float t = (float)yv[j] * (z / (1.f + expf(-z)));
            v[i][j] = t;
            ss += t * t;
        }
    }
#pragma unroll
    for (int off = 32; off > 0; off >>= 1) ss += __shfl_down(ss, off, 64);
    __shared__ float red[4];
    __shared__ float scs;
    if ((tid & 63) == 0) red[tid >> 6] = ss;
    __syncthreads();
    if (tid == 0) scs = rsqrtf((red[0] + red[1] + red[2] + red[3]) * (1.f / INNER) + 1e-6f);
    __syncthreads();
    float scale = scs;
#pragma unroll
    for (int i = 0; i < 2; ++i) {
        const f4* nw = (const f4*)(norm_w + (i * 256 + tid) * 8);
        f4 w0 = nw[0], w1 = nw[1];
        bf16x8 o;
#pragma unroll
        for (int j = 0; j < 4; ++j) {
            o[j]     = (__bf16)(v[i][j]     * scale * w0[j]);
            o[j + 4] = (__bf16)(v[i][j + 4] * scale * w1[j]);
        }
        yrow[i * 256 + tid] = o;
    }
}

extern "C" void kernel_launch(void* const* d_in, const int* in_sizes, int n_in,
                              void* d_out, int out_size, void* d_ws, size_t ws_size,
                              hipStream_t stream) {
    const float* x       = (const float*)d_in[0];
    const float* W_in    = (const float*)d_in[1];
    const float* b_in    = (const float*)d_in[2];
    const float* conv_w  = (const float*)d_in[3];
    const float* conv_b  = (const float*)d_in[4];
    const float* A_log   = (const float*)d_in[5];
    const float* dt_bias = (const float*)d_in[6];
    const float* D_par   = (const float*)d_in[7];
    const float* norm_w  = (const float*)d_in[8];
    const float* W_out   = (const float*)d_in[9];
    const float* b_out   = (const float*)d_in[10];
    float* out = (float*)d_out;

    char* ws = (char*)d_ws;
    constexpr size_t SZ_XBF    = (size_t)ROWS * NH * 2;
    constexpr size_t SZ_WTIN   = (size_t)NPROJ_P * NH * 2;
    constexpr size_t SZ_R1     = SZ_XBF + SZ_WTIN;
    constexpr size_t SZ_ZF     = (size_t)ROWS * INNER * 2;
    constexpr size_t SZ_XBC    = (size_t)ROWS * CONVD * 2;
    constexpr size_t SZ_STATES = (size_t)NBC * HEADS * HDIM * DSTATE * 2;
    constexpr size_t SZ_CBT    = (size_t)NBC * CH * CH * 4;
    constexpr size_t SZ_ACUM   = (size_t)BATCH * HEADS * NC * CH * 4;
    constexpr size_t SZ_AEND   = (size_t)BATCH * HEADS * NC * 4;
    constexpr size_t SZ_DTP    = (size_t)ROWS * HEADS * 4;

    __bf16* xbf    = (__bf16*)(ws);
    __bf16* wtin   = (__bf16*)(ws + SZ_XBF);
    __bf16* zf     = (__bf16*)(ws + SZ_R1);
    __bf16* xbcpre = (__bf16*)(ws + SZ_R1 + SZ_ZF);
    __bf16* xbc    = (__bf16*)(ws + SZ_R1 + SZ_ZF + SZ_XBC);
    float*  dtraw  = (float*) (ws + SZ_R1 + SZ_ZF + 2 * SZ_XBC);
    __bf16* states = (__bf16*)(ws);
    float*  cbT    = (float*) (ws + SZ_STATES);
    float*  acum   = (float*) (ws + SZ_STATES + SZ_CBT);
    float*  aend   = (float*) (ws + SZ_STATES + SZ_CBT + SZ_ACUM);
    float*  dtp_t  = (float*) (ws + SZ_STATES + SZ_CBT + SZ_ACUM + SZ_AEND);
    __bf16* BtG    = (__bf16*)(ws + SZ_STATES + SZ_CBT + SZ_ACUM + SZ_AEND + SZ_DTP);
    __bf16* ybuf   = xbcpre;
    __bf16* wtout  = xbc;
    __bf16* xT     = (__bf16*)out;

    (void)ws_size; (void)in_sizes; (void)n_in; (void)out_size;

    hipFuncSetAttribute(reinterpret_cast<const void*>(&k_gemm8<256,256,2,4,1>),
                        hipFuncAttributeMaxDynamicSharedMemorySize, 131072);
    hipFuncSetAttribute(reinterpret_cast<const void*>(&k_gemm8<256,128,4,2,0>),
                        hipFuncAttributeMaxDynamicSharedMemorySize, 98304);

    k_cast_bf16<<<(ROWS * NH / 4 + 255) / 256, 256, 0, stream>>>(x, xbf, ROWS * NH / 4);
    k_transpose_cast<<<dim3(NPROJ_P / 32, NH / 32), 256, 0, stream>>>(W_in, wtin, NH, NPROJ, NPROJ_P);

    k_gemm8<256,256,2,4,1><<<(NPROJ_P / 256) * (ROWS / 256), 512, 131072, stream>>>(
        xbf, wtin, b_in, nullptr, zf, xbcpre, dtraw, NPROJ_P, NH, ROWS / 256);

    k_conv_silu<<<ROWS * (CONVD / 8) / 256, 256, 0, stream>>>(xbcpre, conv_w, conv_b, xbc);
    k_dt<<<ROWS * HEADS / 256, 256, 0, stream>>>(dtraw, dt_bias, dtp_t);
    k_transpose_bc<<<NBC * 132, 256, 0, stream>>>(xbc, xT, BtG);
    k_cb<<<NBC * 8, 256, 0, stream>>>(xbc, cbT);
    k_states<<<NBC * HEADS, 256, 0, stream>>>(xT, BtG, dtp_t, A_log, states, acum, aend);
    k_scan<<<BATCH * HEADS * 8, 128, 0, stream>>>(states, aend);
    k_out<<<NBC * HEADS, 256, 0, stream>>>(xbc, xT, dtp_t, cbT, states, acum, D_par, ybuf);
    k_gate_norm<<<ROWS, 256, 0, stream>>>(ybuf, zf, norm_w);

    k_transpose_cast<<<dim3(NH / 32, INNER / 32), 256, 0, stream>>>(W_out, wtout, INNER, NH, NH);
    k_gemm8<256,128,4,2,0><<<(NH / 128) * (ROWS / 256), 512, 98304, stream>>>(
        ybuf, wtout, b_out, out, nullptr, nullptr, nullptr, NH, INNER, ROWS / 256);
}

// Round 6
// 460.265 us; speedup vs baseline: 1.1543x; 1.1543x over previous
//
#include <hip/hip_runtime.h>
#include <hip/hip_bf16.h>
#include <cstdint>

typedef __bf16 bf16x8 __attribute__((ext_vector_type(8)));
typedef __bf16 bf16x4 __attribute__((ext_vector_type(4)));
typedef float  f4     __attribute__((ext_vector_type(4)));

constexpr int BATCH   = 2;
constexpr int LSEQ    = 2048;
constexpr int NH      = 2048;
constexpr int INNER   = 4096;
constexpr int DSTATE  = 128;
constexpr int CONVD   = 4352;
constexpr int HEADS   = 64;
constexpr int HDIM    = 64;
constexpr int NPROJ   = 8512;
constexpr int NPROJ_P = 8704;   // padded to 256 multiple
constexpr int NC      = 16;
constexpr int CH      = 128;
constexpr int ROWS    = BATCH * LSEQ;
constexpr int NBC     = BATCH * NC;   // 32

__device__ __forceinline__ f4 f4zero() { f4 v; v.x=0.f; v.y=0.f; v.z=0.f; v.w=0.f; return v; }

__device__ __forceinline__ void gload16(const __bf16* g, const char* l) {
    __builtin_amdgcn_global_load_lds((const __attribute__((address_space(1))) void*)g,
                                     (__attribute__((address_space(3))) void*)l, 16, 0, 0);
}

// ---------------- cast f32 -> bf16 ----------------
__global__ __launch_bounds__(256) void k_cast_bf16(const float* __restrict__ in,
                                                   __bf16* __restrict__ out, int n4) {
    int i = blockIdx.x * 256 + threadIdx.x;
    if (i >= n4) return;
    f4 v = ((const f4*)in)[i];
    bf16x4 o;
    o[0] = (__bf16)v.x; o[1] = (__bf16)v.y; o[2] = (__bf16)v.z; o[3] = (__bf16)v.w;
    ((bf16x4*)out)[i] = o;
}

// ---------------- transpose + cast: in f32 (R x C) -> out bf16 (Cp x R) ----------------
__global__ __launch_bounds__(256) void k_transpose_cast(const float* __restrict__ in,
                                                        __bf16* __restrict__ out,
                                                        int R, int C, int Cp) {
    __shared__ float tile[32][33];
    int bn = blockIdx.x * 32, bk = blockIdx.y * 32;
    int tx = threadIdx.x & 31, ty = threadIdx.x >> 5;
#pragma unroll
    for (int i = 0; i < 4; ++i) {
        int k = bk + ty + i * 8, n = bn + tx;
        tile[ty + i * 8][tx] = (k < R && n < C) ? in[(size_t)k * C + n] : 0.f;
    }
    __syncthreads();
#pragma unroll
    for (int i = 0; i < 4; ++i) {
        int n = bn + ty + i * 8, k = bk + tx;
        if (n < Cp && k < R) out[(size_t)n * R + k] = (__bf16)tile[tx][ty + i * 8];
    }
}

// ============ 2-phase/K-tile 256-tile GEMM: reg-dbuf operands + counted vmcnt ============
// LDS per buffer: A region [kp(2)][row(BM)][32 bf16], then B region same with BN.
// XOR swizzle: k-slot bit1 ^= row bit3 (inverse on staging source, forward on reads).
// Per K-tile: phase0 {12 ds_read(ks=1) + stage 4..LT-1 of t+1 -> MFMA(ks=0)};
//             phase1 {lgkm0+bar -> stage 0..3 of t+2 -> MFMA(ks=1)}; boundary vmcnt(4)+bar.
template<int BM, int BN, int WM, int WN, int EPI>
__global__ __launch_bounds__(512, 2) void k_gemm8(
    const __bf16* __restrict__ A, const __bf16* __restrict__ Bt,
    const float* __restrict__ bias, float* __restrict__ Cf,
    __bf16* __restrict__ zf, __bf16* __restrict__ xbcpre, float* __restrict__ dtraw,
    int N, int K, int gridY) {
    extern __shared__ char smem[];
    constexpr int MFRAG = BM / (WM * 16);
    constexpr int NFRAG = BN / (WN * 16);
    constexpr int ALINES = BM / 64, BLINES = BN / 64, LT = ALINES + BLINES;
    constexpr int ABYTES = BM * 128, BUFB = ABYTES + BN * 128;
    constexpr int LPPA = BM / 128, LPPB = BN / 128;

    int tid = threadIdx.x, lane = tid & 63, w = tid >> 6;
    int wm = w / WN, wn = w % WN;

    // XCD-bijective chunked swizzle, column-major over the grid
    int bid = blockIdx.x;
    int q = gridDim.x >> 3;
    int wg = (bid & 7) * q + (bid >> 3);
    int bx = wg / gridY, by = wg - bx * gridY;
    int mBase = by * BM, nBase = bx * BN;

    // read-side lane constants
    int rl = lane & 15, rq = lane >> 4;
    int kslp = rq ^ (((rl >> 3) & 1) << 1);
    const int rdA = (wm * MFRAG * 16 + rl) * 64 + kslp * 16;
    const int rdB = ABYTES + (wn * NFRAG * 16 + rl) * 64 + kslp * 16;

    // stage-side lane constants (inverse swizzle on source)
    int lanep = lane ^ (((lane >> 5) & 1) << 1);
    int srs = lanep >> 2, sksl = lanep & 3;

    const __bf16* sA[ALINES];
#pragma unroll
    for (int li = 0; li < ALINES; ++li)
        sA[li] = A + (size_t)(mBase + (li % LPPA) * 128 + w * 16 + srs) * K + (li / LPPA) * 32 + sksl * 8;
    const __bf16* sB[BLINES];
#pragma unroll
    for (int li = 0; li < BLINES; ++li)
        sB[li] = Bt + (size_t)(nBase + (li % LPPB) * 128 + w * 16 + srs) * K + (li / LPPB) * 32 + sksl * 8;

    auto stage = [&](int buf, int line, int kt) {
        if (line < ALINES) {
            gload16(sA[line] + kt, smem + buf * BUFB + line * 8192 + w * 1024);
        } else {
            int lb = line - ALINES;
            gload16(sB[lb] + kt, smem + buf * BUFB + ABYTES + lb * 8192 + w * 1024);
        }
    };

    bf16x8 a0[MFRAG], b0[NFRAG], a1[MFRAG], b1[NFRAG];
    auto ldregs = [&](int bufoff, int ks, bf16x8* ar, bf16x8* br) {
#pragma unroll
        for (int i = 0; i < MFRAG; ++i)
            ar[i] = *(const bf16x8*)(smem + bufoff + ks * (BM * 64) + rdA + i * 1024);
#pragma unroll
        for (int i = 0; i < NFRAG; ++i)
            br[i] = *(const bf16x8*)(smem + bufoff + ks * (BN * 64) + rdB + i * 1024);
    };

    f4 acc[MFRAG][NFRAG];
#pragma unroll
    for (int i = 0; i < MFRAG; ++i)
#pragma unroll
        for (int j = 0; j < NFRAG; ++j) acc[i][j] = f4zero();

    auto domfma = [&](bf16x8* ar, bf16x8* br) {
        __builtin_amdgcn_s_setprio(1);
#pragma unroll
        for (int mi = 0; mi < MFRAG; ++mi)
#pragma unroll
            for (int ni = 0; ni < NFRAG; ++ni)
                acc[mi][ni] = __builtin_amdgcn_mfma_f32_16x16x32_bf16(ar[mi], br[ni], acc[mi][ni], 0, 0, 0);
        __builtin_amdgcn_s_setprio(0);
    };

    const int nt = K >> 6;   // assumes nt >= 2
    // prologue: full tile 0 -> buf0; lines 0..3 of tile 1 -> buf1
#pragma unroll
    for (int li = 0; li < LT; ++li) stage(0, li, 0);
#pragma unroll
    for (int li = 0; li < 4; ++li) stage(1, li, 64);
    asm volatile("s_waitcnt vmcnt(4)" ::: "memory");
    __builtin_amdgcn_s_barrier();
    ldregs(0, 0, a0, b0);

    for (int t = 0; t < nt; ++t) {
        const int cur = t & 1;
        const int bufoff = cur * BUFB;
        // ---- phase 0: issue ks=1 reads + finish staging tile t+1; MFMA on ks=0 regs
        ldregs(bufoff, 1, a1, b1);
        if (t + 1 < nt) {
#pragma unroll
            for (int li = 4; li < LT; ++li) stage(cur ^ 1, li, (t + 1) << 6);
        }
        __builtin_amdgcn_sched_barrier(0);   // pin reads+stages before the MFMA block
        domfma(a0, b0);
        // ---- phase 1: buf[cur] reads drained -> safe to stage tile t+2 into it
        asm volatile("s_waitcnt lgkmcnt(0)" ::: "memory");
        __builtin_amdgcn_sched_barrier(0);
        __builtin_amdgcn_s_barrier();
        if (t + 2 < nt) {
#pragma unroll
            for (int li = 0; li < 4; ++li) stage(cur, li, (t + 2) << 6);
        }
        __builtin_amdgcn_sched_barrier(0);
        domfma(a1, b1);
        // ---- boundary: tile t+1 resident -> preload its ks=0 regs
        if (t + 1 < nt) {
            if (t + 2 < nt) {
                asm volatile("s_waitcnt vmcnt(4)" ::: "memory");
            } else {
                asm volatile("s_waitcnt vmcnt(0)" ::: "memory");
            }
            __builtin_amdgcn_s_barrier();
            ldregs((cur ^ 1) * BUFB, 0, a0, b0);
        }
    }

    // epilogue: C/D layout col=lane&15, row=(lane>>4)*4+j
    int cl = lane & 15, rq4 = (lane >> 4) * 4;
#pragma unroll
    for (int nf = 0; nf < NFRAG; ++nf) {
        int col0 = nBase + wn * NFRAG * 16 + nf * 16;
        int col = col0 + cl;
        if constexpr (EPI == 1) {
            if (col0 >= NPROJ) continue;
            float bvv = bias[col];
#pragma unroll
            for (int mf = 0; mf < MFRAG; ++mf) {
#pragma unroll
                for (int j = 0; j < 4; ++j) {
                    int row = mBase + wm * MFRAG * 16 + mf * 16 + rq4 + j;
                    float v = acc[mf][nf][j] + bvv;
                    if (col0 < INNER) {
                        zf[(size_t)row * INNER + col] = (__bf16)v;
                    } else if (col0 < INNER + CONVD) {
                        xbcpre[(size_t)row * CONVD + (col - INNER)] = (__bf16)v;
                    } else {
                        dtraw[(size_t)row * HEADS + (col - INNER - CONVD)] = v;
                    }
                }
            }
        } else {
            float bvv = bias[col];
#pragma unroll
            for (int mf = 0; mf < MFRAG; ++mf)
#pragma unroll
                for (int j = 0; j < 4; ++j) {
                    int row = mBase + wm * MFRAG * 16 + mf * 16 + rq4 + j;
                    Cf[(size_t)row * N + col] = acc[mf][nf][j] + bvv;
                }
        }
    }
}

// ---------------- depthwise causal conv(4) + bias + silu ----------------
__global__ __launch_bounds__(256) void k_conv_silu(const __bf16* __restrict__ xbcpre,
                                                   const float* __restrict__ conv_w,
                                                   const float* __restrict__ conv_b,
                                                   __bf16* __restrict__ xbc) {
    int idx = blockIdx.x * 256 + threadIdx.x;
    int c8 = idx % (CONVD / 8);
    int bl = idx / (CONVD / 8);
    int l = bl & (LSEQ - 1);
    int c0 = c8 * 8;
    float acc[8];
    const f4* cb4 = (const f4*)(conv_b + c0);
    f4 b0 = cb4[0], b1 = cb4[1];
#pragma unroll
    for (int k = 0; k < 4; ++k) { acc[k] = b0[k]; acc[k + 4] = b1[k]; }
#pragma unroll
    for (int j = 0; j < 4; ++j) {
        int l2 = l + j - 3;
        if (l2 < 0) continue;
        bf16x8 xv = *(const bf16x8*)(xbcpre + (size_t)(bl + j - 3) * CONVD + c0);
        const f4* w4 = (const f4*)(conv_w + j * CONVD + c0);
        f4 w0 = w4[0], w1 = w4[1];
#pragma unroll
        for (int k = 0; k < 4; ++k) {
            acc[k]     += w0[k] * (float)xv[k];
            acc[k + 4] += w1[k] * (float)xv[k + 4];
        }
    }
    bf16x8 o;
#pragma unroll
    for (int k = 0; k < 8; ++k) {
        float a = acc[k];
        o[k] = (__bf16)(a / (1.f + expf(-a)));
    }
    *(bf16x8*)(xbc + (size_t)bl * CONVD + c0) = o;
}

// ---------------- dt = clip(softplus(raw+bias)), stored transposed [b,h][l] ----------------
__global__ __launch_bounds__(256) void k_dt(const float* __restrict__ dtraw,
                                            const float* __restrict__ dt_bias,
                                            float* __restrict__ dtp_t) {
    int idx = blockIdx.x * 256 + threadIdx.x;  // ROWS*HEADS
    int h = idx & 63;
    int bl = idx >> 6;
    int b = bl >> 11, l = bl & (LSEQ - 1);
    float raw = dtraw[idx] + dt_bias[h];
    float sp = raw > 20.f ? raw : log1pf(expf(raw));
    dtp_t[((size_t)(b * HEADS + h)) * LSEQ + l] = fminf(fmaxf(sp, 0.001f), 0.1f);
}

// ---------------- per-(b,c): transpose x-block and B-block ----------------
__global__ __launch_bounds__(256) void k_transpose_bc(const __bf16* __restrict__ xbc,
                                                      __bf16* __restrict__ xT,
                                                      __bf16* __restrict__ BtG) {
    int bid = blockIdx.x;                 // bc*132 + rt*66 + ct
    int ct = bid % 66;
    int rt = (bid / 66) & 1;
    int bc = bid / 132;
    __shared__ float T[64][65];
    int t = threadIdx.x;
    int lr0 = t >> 3, cg = t & 7;
#pragma unroll
    for (int it = 0; it < 2; ++it) {
        int lr = lr0 + it * 32;
        bf16x8 v = *(const bf16x8*)(xbc + (size_t)(bc * CH + rt * 64 + lr) * CONVD + ct * 64 + cg * 8);
#pragma unroll
        for (int j = 0; j < 8; ++j) T[lr][cg * 8 + j] = (float)v[j];
    }
    __syncthreads();
#pragma unroll
    for (int it = 0; it < 2; ++it) {
        int cl = lr0 + it * 32;
        int c = ct * 64 + cl;
        bf16x8 o;
#pragma unroll
        for (int j = 0; j < 8; ++j) o[j] = (__bf16)T[cg * 8 + j][cl];
        __bf16* dst = (c < INNER)
            ? xT  + ((size_t)bc * INNER + c) * CH + rt * 64 + cg * 8
            : BtG + ((size_t)bc * DSTATE + (c - INNER)) * CH + rt * 64 + cg * 8;
        *(bf16x8*)dst = o;
    }
}

// ---------------- cb[bc][l][s] = C[l]·B[s] (lower-tri) ----------------
__global__ __launch_bounds__(256) void k_cb(const __bf16* __restrict__ xbc,
                                            float* __restrict__ cbT) {
    int bid = blockIdx.x;  // bc*8 + lg
    int lg = bid & 7, bc = bid >> 3;
    int tid = threadIdx.x;
    int e0 = lg * 2048 + tid * 8;
    int l = e0 >> 7;
    int s0 = e0 & 127;
    const __bf16* Crow = xbc + (size_t)(bc * CH + l) * CONVD + INNER + DSTATE;
    const __bf16* B0   = xbc + (size_t)(bc * CH + s0) * CONVD + INNER;
    float acc[8];
#pragma unroll
    for (int j = 0; j < 8; ++j) acc[j] = 0.f;
    for (int n8 = 0; n8 < 16; ++n8) {
        bf16x8 cv = *(const bf16x8*)(Crow + n8 * 8);
        float cf[8];
#pragma unroll
        for (int k = 0; k < 8; ++k) cf[k] = (float)cv[k];
#pragma unroll
        for (int j = 0; j < 8; ++j) {
            bf16x8 bvv = *(const bf16x8*)(B0 + (size_t)j * CONVD + n8 * 8);
#pragma unroll
            for (int k = 0; k < 8; ++k) acc[j] += cf[k] * (float)bvv[k];
        }
    }
    float* dst = cbT + ((size_t)bc << 14) + (l << 7) + s0;
#pragma unroll
    for (int j = 0; j < 8; ++j) dst[j] = (s0 + j <= l) ? acc[j] : 0.f;
}

// ---------------- k_states (MFMA): states[p][n] = sum_l e[l]*X[l,p]*B[l,n] ----------------
__global__ __launch_bounds__(256) void k_states(const __bf16* __restrict__ xT,
                                                const __bf16* __restrict__ BtG,
                                                const float* __restrict__ dtp_t,
                                                const float* __restrict__ A_log,
                                                __bf16* __restrict__ states,
                                                float* __restrict__ acum_buf,
                                                float* __restrict__ aend_buf) {
    int bid = blockIdx.x;
    int h = bid & 63, c = (bid >> 6) & 15, b = bid >> 10;
    int bc = b * NC + c, bh = b * HEADS + h;
    int tid = threadIdx.x;
    int lane = tid & 63, w = tid >> 6;
    __shared__ __bf16 Ab[64 * 136];
    __shared__ __bf16 Bb[128 * 136];
    __shared__ float s_ac[128], s_dt[128], s_e[128];
    float a_h = -expf(A_log[h]);

    if (tid < 128) {
        float d = dtp_t[(size_t)bh * LSEQ + c * CH + tid];
        s_dt[tid] = d;
        s_ac[tid] = a_h * d;
    }
    __syncthreads();
    for (int offd = 1; offd < 128; offd <<= 1) {
        float v = 0.f;
        if (tid < 128 && tid >= offd) v = s_ac[tid - offd];
        __syncthreads();
        if (tid < 128) s_ac[tid] += v;
        __syncthreads();
    }
    float aend = s_ac[127];
    if (tid < 128) {
        s_e[tid] = expf(aend - s_ac[tid]) * s_dt[tid];
        acum_buf[((size_t)bh * NC + c) * CH + tid] = s_ac[tid];
    }
    if (tid == 0) aend_buf[bh * NC + c] = aend;
    __syncthreads();

    const __bf16* xrow = xT + ((size_t)bc * INNER + h * HDIM) * CH;
#pragma unroll
    for (int it = 0; it < 4; ++it) {
        int task = it * 256 + tid;
        int p = task >> 4, lg2 = task & 15;
        bf16x8 v = *(const bf16x8*)(xrow + (size_t)p * CH + lg2 * 8);
        bf16x8 o;
#pragma unroll
        for (int j = 0; j < 8; ++j) o[j] = (__bf16)((float)v[j] * s_e[lg2 * 8 + j]);
        *(bf16x8*)&Ab[p * 136 + lg2 * 8] = o;
    }
    const __bf16* brow = BtG + (size_t)bc * DSTATE * CH;
#pragma unroll
    for (int it = 0; it < 8; ++it) {
        int task = it * 256 + tid;
        int n = task >> 4, lg2 = task & 15;
        *(bf16x8*)&Bb[n * 136 + lg2 * 8] = *(const bf16x8*)(brow + (size_t)n * CH + lg2 * 8);
    }
    __syncthreads();

    int rl = lane & 15, kq = (lane >> 4) * 8, rq = lane >> 4;
    f4 acc[8];
#pragma unroll
    for (int i = 0; i < 8; ++i) acc[i] = f4zero();
#pragma unroll
    for (int ks = 0; ks < 4; ++ks) {
        int k0 = ks * 32;
        bf16x8 a = *(const bf16x8*)&Ab[(w * 16 + rl) * 136 + k0 + kq];
#pragma unroll
        for (int nf = 0; nf < 8; ++nf) {
            bf16x8 bfr = *(const bf16x8*)&Bb[(nf * 16 + rl) * 136 + k0 + kq];
            acc[nf] = __builtin_amdgcn_mfma_f32_16x16x32_bf16(a, bfr, acc[nf], 0, 0, 0);
        }
    }
    __syncthreads();
#pragma unroll
    for (int nf = 0; nf < 8; ++nf)
#pragma unroll
        for (int j = 0; j < 4; ++j)
            Ab[(w * 16 + rq * 4 + j) * 136 + nf * 16 + rl] = (__bf16)acc[nf][j];
    __syncthreads();
    __bf16* sbase = states + ((size_t)(bc * HEADS + h)) * (HDIM * DSTATE);
#pragma unroll
    for (int it = 0; it < 4; ++it) {
        int task = it * 256 + tid;
        int p = task >> 4, ng = task & 15;
        *(bf16x8*)(sbase + (size_t)p * DSTATE + ng * 8) = *(const bf16x8*)&Ab[p * 136 + ng * 8];
    }
}

// ---------------- inter-chunk state scan (in place, bf16), 8 slices per (b,h) ----------
__global__ __launch_bounds__(128) void k_scan(__bf16* __restrict__ states,
                                              const float* __restrict__ aend_buf) {
    int s = blockIdx.x & 7;
    int bh = blockIdx.x >> 3;
    int b = bh >> 6, h = bh & 63;
    int tid = threadIdx.x;
    size_t off = (size_t)s * 1024 + (size_t)tid * 8;
    float run[8];
#pragma unroll
    for (int j = 0; j < 8; ++j) run[j] = 0.f;
    for (int c = 0; c < NC; ++c) {
        float dec = expf(aend_buf[bh * NC + c]);
        __bf16* base = states + ((size_t)((b * NC + c) * HEADS + h)) * (HDIM * DSTATE) + off;
        bf16x8 sv = *(bf16x8*)base;
        bf16x8 o;
#pragma unroll
        for (int j = 0; j < 8; ++j) o[j] = (__bf16)run[j];
        *(bf16x8*)base = o;
#pragma unroll
        for (int j = 0; j < 8; ++j) run[j] = run[j] * dec + (float)sv[j];
    }
}

// ---------------- k_out (MFMA): y = exp(ac)*C·prev^T + M·X + D*x ----------------
__global__ __launch_bounds__(256) void k_out(const __bf16* __restrict__ xbc,
                                             const __bf16* __restrict__ xT,
                                             const float* __restrict__ dtp_t,
                                             const float* __restrict__ cbT,
                                             const __bf16* __restrict__ prev,
                                             const float* __restrict__ acum_buf,
                                             const float* __restrict__ D_param,
                                             __bf16* __restrict__ ybuf) {
    int bid = blockIdx.x;
    int h = bid & 63, c = (bid >> 6) & 15, b = bid >> 10;
    int bc = b * NC + c, bh = b * HEADS + h;
    int tid = threadIdx.x;
    int lane = tid & 63, w = tid >> 6;
    __shared__ __bf16 Ab[128 * 136];
    __shared__ __bf16 Bb[64 * 136];
    __shared__ float s_ac[128], s_dt[128];
    if (tid < 128) {
        s_ac[tid] = acum_buf[((size_t)bh * NC + c) * CH + tid];
        s_dt[tid] = dtp_t[(size_t)bh * LSEQ + c * CH + tid];
    }

#pragma unroll
    for (int it = 0; it < 8; ++it) {
        int task = it * 256 + tid;
        int l = task >> 4, ng = task & 15;
        *(bf16x8*)&Ab[l * 136 + ng * 8] =
            *(const bf16x8*)(xbc + (size_t)(bc * CH + l) * CONVD + INNER + DSTATE + ng * 8);
    }
    const __bf16* pbase = prev + ((size_t)(bc * HEADS + h)) * (HDIM * DSTATE);
#pragma unroll
    for (int it = 0; it < 4; ++it) {
        int task = it * 256 + tid;
        int p = task >> 4, ng = task & 15;
        *(bf16x8*)&Bb[p * 136 + ng * 8] = *(const bf16x8*)(pbase + (size_t)p * DSTATE + ng * 8);
    }
    __syncthreads();

    int rl = lane & 15, kq = (lane >> 4) * 8, rq = lane >> 4;
    f4 acc[2][4];
#pragma unroll
    for (int i = 0; i < 2; ++i)
#pragma unroll
        for (int j = 0; j < 4; ++j) acc[i][j] = f4zero();

#pragma unroll
    for (int ks = 0; ks < 4; ++ks) {
        int k0 = ks * 32;
        bf16x8 a0 = *(const bf16x8*)&Ab[(w * 32 + rl) * 136 + k0 + kq];
        bf16x8 a1 = *(const bf16x8*)&Ab[(w * 32 + 16 + rl) * 136 + k0 + kq];
#pragma unroll
        for (int nf = 0; nf < 4; ++nf) {
            bf16x8 bfr = *(const bf16x8*)&Bb[(nf * 16 + rl) * 136 + k0 + kq];
            acc[0][nf] = __builtin_amdgcn_mfma_f32_16x16x32_bf16(a0, bfr, acc[0][nf], 0, 0, 0);
            acc[1][nf] = __builtin_amdgcn_mfma_f32_16x16x32_bf16(a1, bfr, acc[1][nf], 0, 0, 0);
        }
    }
#pragma unroll
    for (int mf = 0; mf < 2; ++mf)
#pragma unroll
        for (int j = 0; j < 4; ++j) {
            float el = expf(s_ac[w * 32 + mf * 16 + rq * 4 + j]);
#pragma unroll
            for (int nf = 0; nf < 4; ++nf) acc[mf][nf][j] *= el;
        }
    __syncthreads();

    const float* cbb = cbT + ((size_t)bc << 14);
#pragma unroll
    for (int it = 0; it < 8; ++it) {
        int task = it * 256 + tid;
        int l = task >> 4, sg = task & 15;
        int s0 = sg * 8;
        const f4* cv4 = (const f4*)(cbb + (l << 7) + s0);
        f4 c0 = cv4[0], c1 = cv4[1];
        float acl = s_ac[l];
        bf16x8 o;
#pragma unroll
        for (int j = 0; j < 8; ++j) {
            int s = s0 + j;
            float cj = (j < 4) ? c0[j] : c1[j - 4];
            float m = 0.f;
            if (s <= l) m = cj * expf(acl - s_ac[s]) * s_dt[s];
            o[j] = (__bf16)m;
        }
        *(bf16x8*)&Ab[l * 136 + s0] = o;
    }
    const __bf16* xrow = xT + ((size_t)bc * INNER + h * HDIM) * CH;
#pragma unroll
    for (int it = 0; it < 4; ++it) {
        int task = it * 256 + tid;
        int p = task >> 4, lg2 = task & 15;
        *(bf16x8*)&Bb[p * 136 + lg2 * 8] = *(const bf16x8*)(xrow + (size_t)p * CH + lg2 * 8);
    }
    __syncthreads();

#pragma unroll
    for (int ks = 0; ks < 4; ++ks) {
        int k0 = ks * 32;
        bf16x8 a0 = *(const bf16x8*)&Ab[(w * 32 + rl) * 136 + k0 + kq];
        bf16x8 a1 = *(const bf16x8*)&Ab[(w * 32 + 16 + rl) * 136 + k0 + kq];
#pragma unroll
        for (int nf = 0; nf < 4; ++nf) {
            bf16x8 bfr = *(const bf16x8*)&Bb[(nf * 16 + rl) * 136 + k0 + kq];
            acc[0][nf] = __builtin_amdgcn_mfma_f32_16x16x32_bf16(a0, bfr, acc[0][nf], 0, 0, 0);
            acc[1][nf] = __builtin_amdgcn_mfma_f32_16x16x32_bf16(a1, bfr, acc[1][nf], 0, 0, 0);
        }
    }
    __syncthreads();

    float* yT = (float*)Ab;
#pragma unroll
    for (int mf = 0; mf < 2; ++mf)
#pragma unroll
        for (int nf = 0; nf < 4; ++nf)
#pragma unroll
            for (int j = 0; j < 4; ++j)
                yT[(w * 32 + mf * 16 + rq * 4 + j) * 68 + nf * 16 + rl] = acc[mf][nf][j];
    __syncthreads();

    float dh = D_param[h];
#pragma unroll
    for (int it = 0; it < 4; ++it) {
        int task = it * 256 + tid;
        int l = task >> 3, pg = task & 7;
        const f4* yv4 = (const f4*)&yT[l * 68 + pg * 8];
        f4 y0 = yv4[0], y1 = yv4[1];
        bf16x8 xv = *(const bf16x8*)(xbc + (size_t)(bc * CH + l) * CONVD + h * HDIM + pg * 8);
        bf16x8 o;
#pragma unroll
        for (int j = 0; j < 4; ++j) {
            o[j]     = (__bf16)(y0[j] + dh * (float)xv[j]);
            o[j + 4] = (__bf16)(y1[j] + dh * (float)xv[j + 4]);
        }
        *(bf16x8*)(ybuf + (size_t)(bc * CH + l) * INNER + h * HDIM + pg * 8) = o;
    }
}

// ---------------- gate (silu(z)) + RMSNorm, in place on ybuf ----------------
__global__ __launch_bounds__(256) void k_gate_norm(__bf16* __restrict__ ybuf,
                                                   const __bf16* __restrict__ zf,
                                                   const float* __restrict__ norm_w) {
    int row = blockIdx.x, tid = threadIdx.x;
    bf16x8* yrow = (bf16x8*)(ybuf + (size_t)row * INNER);
    const bf16x8* zrow = (const bf16x8*)(zf + (size_t)row * INNER);
    float v[2][8];
    float ss = 0.f;
#pragma unroll
    for (int i = 0; i < 2; ++i) {
        bf16x8 yv = yrow[i * 256 + tid];
        bf16x8 zv = zrow[i * 256 + tid];
#pragma unroll
        for (int j = 0; j < 8; ++j) {
            float z = (float)zv[j];
            float t = (float)yv[j] * (z / (1.f + expf(-z)));
            v[i][j] = t;
            ss += t * t;
        }
    }
#pragma unroll
    for (int off = 32; off > 0; off >>= 1) ss += __shfl_down(ss, off, 64);
    __shared__ float red[4];
    __shared__ float scs;
    if ((tid & 63) == 0) red[tid >> 6] = ss;
    __syncthreads();
    if (tid == 0) scs = rsqrtf((red[0] + red[1] + red[2] + red[3]) * (1.f / INNER) + 1e-6f);
    __syncthreads();
    float scale = scs;
#pragma unroll
    for (int i = 0; i < 2; ++i) {
        const f4* nw = (const f4*)(norm_w + (i * 256 + tid) * 8);
        f4 w0 = nw[0], w1 = nw[1];
        bf16x8 o;
#pragma unroll
        for (int j = 0; j < 4; ++j) {
            o[j]     = (__bf16)(v[i][j]     * scale * w0[j]);
            o[j + 4] = (__bf16)(v[i][j + 4] * scale * w1[j]);
        }
        yrow[i * 256 + tid] = o;
    }
}

extern "C" void kernel_launch(void* const* d_in, const int* in_sizes, int n_in,
                              void* d_out, int out_size, void* d_ws, size_t ws_size,
                              hipStream_t stream) {
    const float* x       = (const float*)d_in[0];
    const float* W_in    = (const float*)d_in[1];
    const float* b_in    = (const float*)d_in[2];
    const float* conv_w  = (const float*)d_in[3];
    const float* conv_b  = (const float*)d_in[4];
    const float* A_log   = (const float*)d_in[5];
    const float* dt_bias = (const float*)d_in[6];
    const float* D_par   = (const float*)d_in[7];
    const float* norm_w  = (const float*)d_in[8];
    const float* W_out   = (const float*)d_in[9];
    const float* b_out   = (const float*)d_in[10];
    float* out = (float*)d_out;

    char* ws = (char*)d_ws;
    constexpr size_t SZ_XBF    = (size_t)ROWS * NH * 2;
    constexpr size_t SZ_WTIN   = (size_t)NPROJ_P * NH * 2;
    constexpr size_t SZ_R1     = SZ_XBF + SZ_WTIN;
    constexpr size_t SZ_ZF     = (size_t)ROWS * INNER * 2;
    constexpr size_t SZ_XBC    = (size_t)ROWS * CONVD * 2;
    constexpr size_t SZ_STATES = (size_t)NBC * HEADS * HDIM * DSTATE * 2;
    constexpr size_t SZ_CBT    = (size_t)NBC * CH * CH * 4;
    constexpr size_t SZ_ACUM   = (size_t)BATCH * HEADS * NC * CH * 4;
    constexpr size_t SZ_AEND   = (size_t)BATCH * HEADS * NC * 4;
    constexpr size_t SZ_DTP    = (size_t)ROWS * HEADS * 4;

    __bf16* xbf    = (__bf16*)(ws);
    __bf16* wtin   = (__bf16*)(ws + SZ_XBF);
    __bf16* zf     = (__bf16*)(ws + SZ_R1);
    __bf16* xbcpre = (__bf16*)(ws + SZ_R1 + SZ_ZF);
    __bf16* xbc    = (__bf16*)(ws + SZ_R1 + SZ_ZF + SZ_XBC);
    float*  dtraw  = (float*) (ws + SZ_R1 + SZ_ZF + 2 * SZ_XBC);
    __bf16* states = (__bf16*)(ws);
    float*  cbT    = (float*) (ws + SZ_STATES);
    float*  acum   = (float*) (ws + SZ_STATES + SZ_CBT);
    float*  aend   = (float*) (ws + SZ_STATES + SZ_CBT + SZ_ACUM);
    float*  dtp_t  = (float*) (ws + SZ_STATES + SZ_CBT + SZ_ACUM + SZ_AEND);
    __bf16* BtG    = (__bf16*)(ws + SZ_STATES + SZ_CBT + SZ_ACUM + SZ_AEND + SZ_DTP);
    __bf16* ybuf   = xbcpre;
    __bf16* wtout  = xbc;
    __bf16* xT     = (__bf16*)out;

    (void)ws_size; (void)in_sizes; (void)n_in; (void)out_size;

    hipFuncSetAttribute(reinterpret_cast<const void*>(&k_gemm8<256,256,2,4,1>),
                        hipFuncAttributeMaxDynamicSharedMemorySize, 131072);
    hipFuncSetAttribute(reinterpret_cast<const void*>(&k_gemm8<256,128,4,2,0>),
                        hipFuncAttributeMaxDynamicSharedMemorySize, 98304);

    k_cast_bf16<<<(ROWS * NH / 4 + 255) / 256, 256, 0, stream>>>(x, xbf, ROWS * NH / 4);
    k_transpose_cast<<<dim3(NPROJ_P / 32, NH / 32), 256, 0, stream>>>(W_in, wtin, NH, NPROJ, NPROJ_P);

    k_gemm8<256,256,2,4,1><<<(NPROJ_P / 256) * (ROWS / 256), 512, 131072, stream>>>(
        xbf, wtin, b_in, nullptr, zf, xbcpre, dtraw, NPROJ_P, NH, ROWS / 256);

    k_conv_silu<<<ROWS * (CONVD / 8) / 256, 256, 0, stream>>>(xbcpre, conv_w, conv_b, xbc);
    k_dt<<<ROWS * HEADS / 256, 256, 0, stream>>>(dtraw, dt_bias, dtp_t);
    k_transpose_bc<<<NBC * 132, 256, 0, stream>>>(xbc, xT, BtG);
    k_cb<<<NBC * 8, 256, 0, stream>>>(xbc, cbT);
    k_states<<<NBC * HEADS, 256, 0, stream>>>(xT, BtG, dtp_t, A_log, states, acum, aend);
    k_scan<<<BATCH * HEADS * 8, 128, 0, stream>>>(states, aend);
    k_out<<<NBC * HEADS, 256, 0, stream>>>(xbc, xT, dtp_t, cbT, states, acum, D_par, ybuf);
    k_gate_norm<<<ROWS, 256, 0, stream>>>(ybuf, zf, norm_w);

    k_transpose_cast<<<dim3(NH / 32, INNER / 32), 256, 0, stream>>>(W_out, wtout, INNER, NH, NH);
    k_gemm8<256,128,4,2,0><<<(NH / 128) * (ROWS / 256), 512, 98304, stream>>>(
        ybuf, wtout, b_out, out, nullptr, nullptr, nullptr, NH, INNER, ROWS / 256);
}